// Round 8
// baseline (113.021 us; speedup 1.0000x reference)
//
#include <hip/hip_runtime.h>

// KANLayer: B=1024, I=64, O=64, H=32. ALL I/O float32 (per reference).
// out[b,o] = sum_i [ bw[o,i]*leaky(x[b,i]) + lw[o,i]*( sum_k W3[o,i,k]*h2[k] + b3[o,i] ) ]
//   h1[h] = leaky(x[b,i]*W1[o,i,h] + b1[o,i,h])
//   h2[k] = leaky(sum_h h1[h]*W2[o,i,k,h] + b2[o,i,k])
//
// R20 = R19 with the tile split as a PURE TLP knob (clean re-test of R16).
// R19 post-mortem: staging exonerated (~-0.8us for -100 VALU staging); main
// ~29us is loop-body latency: issue-arith says 4 waves/SIMD x (100 VALU*2 +
// 12 MFMA*5) ~ 1120 cyc/ii vs 4500 observed -> 25% issue-busy, 75% stall.
// R16's ROWS=32/MT=2 regression had two confounds, both now GONE:
//   (a) fat staging (~100 VALU) doubled with 2x blocks -> now ~20 VALU copies
//   (b) 16 pkrtz/ii W2 repack amortized over MT -> now pre-repacked, zero.
// R20: ROWS=32, MT=2, grid (64,32)=2048 blocks. LDS 29.8KB -> 5 blocks/CU
// = 20 waves/CU (62% vs 50%). Per-wave issue work halves at fixed latency
// structure. launch_bounds(256,5): VGPR cap 102, MT=2 working set ~70-80
// (leaner than R18's which fit under 128). Loop body / pre-kernel / W2H
// addressing verbatim R19. One variable changed.
// Verify: no spill (WRITE ~2MB if visible), total 102-106. Neutral ->
// per-ii overhead is the cost (R21: loop body). >115 -> TLP refuted
// (R21: merge pre into main).

#define H_   32
#define NI   64
#define NO   64
#define NB   1024
#define ROWS 32     // batch rows per block (2 m-tiles)
#define MT   2      // m-tiles per wave
#define XSTR 66     // x LDS row stride (uint pairs): 8B-aligned, 2-way banks (free)
#define NWAVE 4
#define ISL  16     // i-slice width per wave
#define RSEG 8      // rc-loop parallel segments

// ---- workspace layout (bytes) ----
#define W2H_OFF 0
#define W2H_BYTES 8388608            // 64*64*1024 f16 frags = 8.4 MB
#define QS_OFF   8388608
#define QS_BYTES 262144              // 64*64*32 f16
#define RB_OFF   8650752
#define RB_BYTES 16384               // 64*64 f32
#define XD_OFF   8667136
#define XD_BYTES 262144              // 1024*64 dup-f16 pairs (u32)
#define W1H_OFF  8929280
#define W1H_BYTES 262144             // 64*64*32 f16
#define B1H_OFF  9191424
#define B1H_BYTES 262144
#define WBP_OFF  9453568
#define WBP_BYTES 524288             // 64*64*32 u32 pairs
#define WS_NEED  9977856

typedef float    floatx4 __attribute__((ext_vector_type(4)));
typedef _Float16 halfx8  __attribute__((ext_vector_type(8)));
typedef _Float16 halfx2  __attribute__((ext_vector_type(2)));

union H8 { halfx8 v8; halfx2 v2[4]; unsigned int u[4]; };

__device__ inline float leaky(float v) { return fmaxf(v, 0.01f * v); }

__device__ inline unsigned int pkrtz(float a, float b) {   // (a,b) -> f16x2, RTZ
    return __builtin_bit_cast(unsigned int, __builtin_amdgcn_cvt_pkrtz(a, b));
}

// ================= pre-kernel (R19 verbatim) =================
// ranges: [0,524288) W2 repack; +131072 q; +4096 rb; +16384 xd; +16384 w1h;
//         +16384 b1h; +16384 wbp.  total 724992 thr = 2832 blocks.
__global__ __launch_bounds__(256)
void kan_pre(const float* __restrict__ x,  const float* __restrict__ W1,
             const float* __restrict__ b1, const float* __restrict__ W2,
             const float* __restrict__ b2, const float* __restrict__ W3,
             const float* __restrict__ lw,
             _Float16* __restrict__ w2h, _Float16* __restrict__ qs,
             float* __restrict__ rb, unsigned int* __restrict__ xd,
             _Float16* __restrict__ w1h, _Float16* __restrict__ b1h,
             unsigned int* __restrict__ wbp)
{
    const int tid = blockIdx.x * 256 + threadIdx.x;
    if (tid < 524288) {
        // W2 -> f16 MFMA fragments, dest-linear: tid -> (o,i,f,lane)
        const int lane = tid & 63, f = (tid >> 6) & 1, i = (tid >> 7) & 63, o = tid >> 13;
        const int col = lane & 15, kh = lane >> 4;
        const float* src = W2 + (((size_t)(o * 64 + i) * 32 + f * 16 + col) * 32 + kh * 8);
        float4 s0 = *(const float4*)src;
        float4 s1 = *(const float4*)(src + 4);
        uint4 p = { pkrtz(s0.x, s0.y), pkrtz(s0.z, s0.w),
                    pkrtz(s1.x, s1.y), pkrtz(s1.z, s1.w) };
        *(uint4*)(w2h + (size_t)tid * 8) = p;
    } else if (tid < 655360) {
        // q[oi,h] = .505*lw*sum_k w3_k*W2[k,h]
        const int qt = tid - 524288;
        const int h = qt & 31, oi = qt >> 5;
        const float* w2p = W2 + (size_t)oi * 1024 + h;
        const float* w3p = W3 + (size_t)oi * 32;
        float acc = 0.f;
        #pragma unroll 8
        for (int k = 0; k < 32; ++k) acc += w3p[k] * w2p[k * 32];
        qs[(size_t)oi * 32 + h] = (_Float16)(0.505f * lw[oi] * acc);
    } else if (tid < 659456) {
        // rbias[oi] = .505*lw*sum_k w3_k*b2_k
        const int oi = tid - 655360;
        const float* w3p = W3 + (size_t)oi * 32;
        const float* b2p = b2 + (size_t)oi * 32;
        float acc = 0.f;
        #pragma unroll 8
        for (int k = 0; k < 32; ++k) acc += w3p[k] * b2p[k];
        rb[oi] = 0.505f * lw[oi] * acc;
    } else if (tid < 675840) {
        // x -> duplicated f16 pairs
        const int j = tid - 659456;
        const int fe = j * 4;
        float4 xv = *(const float4*)(x + fe);
        uint4 p = { pkrtz(xv.x, xv.x), pkrtz(xv.y, xv.y),
                    pkrtz(xv.z, xv.z), pkrtz(xv.w, xv.w) };
        *(uint4*)(xd + fe) = p;
    } else if (tid < 692224) {
        // W1 -> f16
        const int j = tid - 675840;
        const float* s = W1 + (size_t)j * 8;
        float4 a = *(const float4*)s, c = *(const float4*)(s + 4);
        uint4 p = { pkrtz(a.x, a.y), pkrtz(a.z, a.w),
                    pkrtz(c.x, c.y), pkrtz(c.z, c.w) };
        *(uint4*)(w1h + (size_t)j * 8) = p;
    } else if (tid < 708608) {
        // b1 -> f16
        const int j = tid - 692224;
        const float* s = b1 + (size_t)j * 8;
        float4 a = *(const float4*)s, c = *(const float4*)(s + 4);
        uint4 p = { pkrtz(a.x, a.y), pkrtz(a.z, a.w),
                    pkrtz(c.x, c.y), pkrtz(c.z, c.w) };
        *(uint4*)(b1h + (size_t)j * 8) = p;
    } else if (tid < 724992) {
        // wbp[oi*32+k] = pk(.495*lw*w3, b2)
        const int j = tid - 708608;
        const int e = j * 8, oi = e >> 5;
        const float l = 0.495f * lw[oi];
        const float* w3g = W3 + e;
        const float* b2g = b2 + e;
        float4 wa = *(const float4*)(w3g), wb = *(const float4*)(w3g + 4);
        float4 ba = *(const float4*)(b2g), bb = *(const float4*)(b2g + 4);
        uint4 p0 = { pkrtz(l * wa.x, ba.x), pkrtz(l * wa.y, ba.y),
                     pkrtz(l * wa.z, ba.z), pkrtz(l * wa.w, ba.w) };
        uint4 p1 = { pkrtz(l * wb.x, bb.x), pkrtz(l * wb.y, bb.y),
                     pkrtz(l * wb.z, bb.z), pkrtz(l * wb.w, bb.w) };
        *(uint4*)(&wbp[e])     = p0;
        *(uint4*)(&wbp[e + 4]) = p1;
    }
}

// ================= main kernel (R19 loop verbatim, ROWS=32/MT=2) =================
__global__ __launch_bounds__(256, 5)
void kan_kernel(const unsigned int* __restrict__ xd, const _Float16* __restrict__ w1h,
                const _Float16* __restrict__ b1h, const unsigned int* __restrict__ wbp,
                const _Float16* __restrict__ qsg, const float* __restrict__ rb,
                const float* __restrict__ b3,  const float* __restrict__ lw,
                const float* __restrict__ bw,  const _Float16* __restrict__ w2h,
                float* __restrict__ out)
{
    __shared__ unsigned int xsp[ROWS * XSTR];  // x dup-f16 pairs, 8.25 KB
    __shared__ _Float16 w1s[NI * H_];          // 4 KB
    __shared__ _Float16 b1s[NI * H_];          // 4 KB
    __shared__ unsigned int wbs[NI * H_];      // {.495*lw*w3, b2} f16 pairs, 8 KB
    __shared__ _Float16 qsl[NI * H_];          // q staged, 4 KB
    __shared__ float rcs[RSEG][ROWS];          // per-seg row constants, 1 KB
    __shared__ float part[NWAVE][ROWS];        // per-wave i-slice partials, 512 B

    const int t    = threadIdx.x;
    const int o    = blockIdx.x;               // o fastest -> same-o blocks share XCD
    const int row0 = blockIdx.y * ROWS;

    // ---- stage x tile: pure copy from pre-converted xd ----
    const unsigned int* xdp = xd + (size_t)row0 * NI;
    #pragma unroll
    for (int v = 0; v < 2; ++v) {
        int fe = (v * 256 + t) * 4;            // u32 index, multiple of 4
        int r = fe >> 6, c = fe & 63;
        uint4 w = *(const uint4*)(xdp + fe);
        uint2 lo = { w.x, w.y };
        uint2 hi = { w.z, w.w };
        *(uint2*)(&xsp[r * XSTR + c])     = lo;   // 66r+c even -> 8B aligned
        *(uint2*)(&xsp[r * XSTR + c + 2]) = hi;
    }
    // ---- stage W1/b1/wbs/q: pure copies ----
    *(uint4*)(w1s + t * 8) = *(const uint4*)(w1h + (size_t)o * (NI * H_) + t * 8);
    *(uint4*)(b1s + t * 8) = *(const uint4*)(b1h + (size_t)o * (NI * H_) + t * 8);
    {
        const unsigned int* wp = wbp + (size_t)o * (NI * H_);  // o*2048
        *(uint4*)(&wbs[t * 8])     = *(const uint4*)(wp + t * 8);
        *(uint4*)(&wbs[t * 8 + 4]) = *(const uint4*)(wp + t * 8 + 4);
    }
    *(uint4*)(qsl + t * 8) = *(const uint4*)(qsg + (size_t)o * (NI * H_) + t * 8);
    __syncthreads();

    const int lane = t & 63, wave = t >> 6;
    const int col  = lane & 15;            // MFMA n-index (h2 k-slot) / A m-offset
    const int kh   = lane >> 4;            // contraction quad
    const int koff = kh * 8;
    const int i0   = wave * ISL;           // this wave's i-slice (16 wide)

    const halfx2 slope = { (_Float16)0.01f, (_Float16)0.01f };

    floatx4 pacc[MT];                      // |c| (negative-half) accumulators
    floatx4 acc1[MT];                      // q-MFMA (positive-half) accumulators
    #pragma unroll
    for (int m = 0; m < MT; ++m) {
        pacc[m] = floatx4{0.f, 0.f, 0.f, 0.f};
        acc1[m] = floatx4{0.f, 0.f, 0.f, 0.f};
    }

    // W2 f16 fragments: elem = (o*NI+i)*1024 + f*512 + lane*8
    const _Float16* wbase = w2h + (size_t)(o * NI + i0) * 1024 + (size_t)lane * 8;

    // prime the prefetch registers with iter 0's W2 fragments (R13 shape)
    halfx8 cA = *(const halfx8*)(wbase);
    halfx8 cB = *(const halfx8*)(wbase + 512);

    #pragma unroll 2
    for (int ii = 0; ii < ISL; ++ii) {
        const int i = i0 + ii;

        // issue next iteration's W2 loads before consuming this one's
        halfx8 nA, nB;
        if (ii < ISL - 1) {
            const _Float16* np = wbase + (ii + 1) * 1024;
            nA = *(const halfx8*)(np);
            nB = *(const halfx8*)(np + 512);
        }

        H8 w1v, b1v, qf;
        w1v.v8 = *(const halfx8*)(w1s + i * H_ + koff);
        b1v.v8 = *(const halfx8*)(b1s + i * H_ + koff);
        qf.v8  = *(const halfx8*)(qsl + i * H_ + koff);

        // per-k constants from LDS: {.495*lw*w3, b2} f16 pairs (broadcast reads)
        halfx2 q0 = __builtin_bit_cast(halfx2, wbs[i * H_ + col]);
        halfx2 q1 = __builtin_bit_cast(halfx2, wbs[i * H_ + col + 16]);
        float nn0 = (float)q0[0], b2c0 = (float)q0[1];
        float nn1 = (float)q1[0], b2c1 = (float)q1[1];

        #pragma unroll
        for (int m = 0; m < MT; ++m) {
            halfx2 xx = __builtin_bit_cast(halfx2, xsp[(m * 16 + col) * XSTR + i]);
            H8 af;
            #pragma unroll
            for (int j = 0; j < 4; ++j) {
                halfx2 h = __builtin_elementwise_fma(xx, w1v.v2[j], b1v.v2[j]);
                af.v2[j] = __builtin_elementwise_max(h, h * slope);  // pk leaky
            }
            floatx4 c0 = { b2c0, b2c0, b2c0, b2c0 };   // b2 folded into C
            floatx4 c1 = { b2c1, b2c1, b2c1, b2c1 };
            c0 = __builtin_amdgcn_mfma_f32_16x16x32_f16(af.v8, cA, c0, 0, 0, 0);
            c1 = __builtin_amdgcn_mfma_f32_16x16x32_f16(af.v8, cB, c1, 0, 0, 0);
            acc1[m] = __builtin_amdgcn_mfma_f32_16x16x32_f16(af.v8, qf.v8, acc1[m], 0, 0, 0);
            // negative-half epilogue only: pacc += (.495*lw*w3)*|c|
            #pragma unroll
            for (int r = 0; r < 4; ++r)
                pacc[m][r] = fmaf(nn0, fabsf(c0[r]),
                             fmaf(nn1, fabsf(c1[r]), pacc[m][r]));
        }

        cA = nA; cB = nB;
    }

    // ---- in-wave reduce over the 16 col lanes, deposit i-slice partials ----
    // acc1 columns are identical (broadcast B) -> add once at col==0, no reduce.
    #pragma unroll
    for (int m = 0; m < MT; ++m) {
        #pragma unroll
        for (int r = 0; r < 4; ++r) {
            float v = pacc[m][r];
            v += __shfl_xor(v, 1, 64);
            v += __shfl_xor(v, 2, 64);
            v += __shfl_xor(v, 4, 64);
            v += __shfl_xor(v, 8, 64);
            if (col == 0)
                part[wave][m * 16 + kh * 4 + r] = v + acc1[m][r];  // C row = kh*4+r
        }
    }

    // ---- per-row constants, 8-way parallel over i-segments ----
    {
        const int row = t & 31, seg = t >> 5;  // 8 segs x 8 i each
        float s = 0.f;
        const float* bwp = bw + o * NI;
        const float* lp  = lw + o * NI;
        const float* b3p = b3 + o * NI;
        const float* rbp = rb + o * NI;
        #pragma unroll
        for (int u = 0; u < NI / RSEG; ++u) {
            int i = seg * (NI / RSEG) + u;
            halfx2 hx = __builtin_bit_cast(halfx2, xsp[row * XSTR + i]);
            s += bwp[i] * leaky((float)hx[0]) + lp[i] * b3p[i] + rbp[i];
        }
        rcs[seg][row] = s;
    }
    __syncthreads();

    // ---- cross-wave sum + per-row constants, write out[b,o] ----
    if (t < ROWS) {
        float v = 0.f;
        #pragma unroll
        for (int w = 0; w < NWAVE; ++w) v += part[w][t];
        #pragma unroll
        for (int s = 0; s < RSEG; ++s) v += rcs[s][t];
        out[(size_t)(row0 + t) * NO + o] = v;
    }
}

// ================= fallback (R16 verbatim, no workspace) =================
__global__ __launch_bounds__(256, 6)
void kan_fb(const float* __restrict__ x,  const float* __restrict__ W1,
            const float* __restrict__ b1, const float* __restrict__ W2,
            const float* __restrict__ b2, const float* __restrict__ W3,
            const float* __restrict__ b3, const float* __restrict__ lw,
            const float* __restrict__ bw, float* __restrict__ out)
{
    __shared__ unsigned int xsp[32 * XSTR];
    __shared__ _Float16 w1s[NI * H_];
    __shared__ _Float16 b1s[NI * H_];
    __shared__ unsigned int wbs[NI * H_];
    __shared__ float rcs[8][32];
    __shared__ float part[4][32];

    const int t    = threadIdx.x;
    const int o    = blockIdx.x;
    const int row0 = blockIdx.y * 32;

    const float* xsrc = x + (size_t)row0 * NI;
    #pragma unroll
    for (int v = 0; v < 2; ++v) {
        int fe = (v * 256 + t) * 4;
        int r = fe >> 6, c = fe & 63;
        float4 xv = *(const float4*)(xsrc + fe);
        uint2 lo = { pkrtz(xv.x, xv.x), pkrtz(xv.y, xv.y) };
        uint2 hi = { pkrtz(xv.z, xv.z), pkrtz(xv.w, xv.w) };
        *(uint2*)(&xsp[r * XSTR + c])     = lo;
        *(uint2*)(&xsp[r * XSTR + c + 2]) = hi;
    }
    const float* w1g = W1 + (size_t)o * NI * H_;
    const float* b1g = b1 + (size_t)o * NI * H_;
    #pragma unroll
    for (int v = 0; v < 2; ++v) {
        int e = (v * 256 + t) * 4;
        float4 a = *(const float4*)(w1g + e);
        float4 c = *(const float4*)(b1g + e);
        uint2 pa = { pkrtz(a.x, a.y), pkrtz(a.z, a.w) };
        uint2 pc = { pkrtz(c.x, c.y), pkrtz(c.z, c.w) };
        *(uint2*)(w1s + e) = pa;
        *(uint2*)(b1s + e) = pc;
    }
    {
        int e = t * 8;
        float l = lw[o * NI + (e >> 5)];
        const float* w3g = W3 + (size_t)o * NI * H_ + e;
        const float* b2g = b2 + (size_t)o * NI * H_ + e;
        float4 wa = *(const float4*)(w3g), wb = *(const float4*)(w3g + 4);
        float4 ba = *(const float4*)(b2g), bb = *(const float4*)(b2g + 4);
        uint4 p0 = { pkrtz(l * wa.x, ba.x), pkrtz(l * wa.y, ba.y),
                     pkrtz(l * wa.z, ba.z), pkrtz(l * wa.w, ba.w) };
        uint4 p1 = { pkrtz(l * wb.x, bb.x), pkrtz(l * wb.y, bb.y),
                     pkrtz(l * wb.z, bb.z), pkrtz(l * wb.w, bb.w) };
        *(uint4*)(&wbs[e])     = p0;
        *(uint4*)(&wbs[e + 4]) = p1;
    }
    __syncthreads();

    const int lane = t & 63, wave = t >> 6;
    const int col  = lane & 15;
    const int kh   = lane >> 4;
    const int koff = kh * 8;
    const int i0   = wave * 16;

    const float* w2p0 = W2 + ((size_t)(o * NI + i0) * H_ + col) * H_ + koff;
    const float* w2p1 = w2p0 + 16 * H_;
    const halfx2 slope = { (_Float16)0.01f, (_Float16)0.01f };

    floatx4 pacc[2];
    #pragma unroll
    for (int m = 0; m < 2; ++m) pacc[m] = floatx4{0.f, 0.f, 0.f, 0.f};

    floatx4 a0 = *(const floatx4*)(w2p0);
    floatx4 a1 = *(const floatx4*)(w2p0 + 4);
    floatx4 a2 = *(const floatx4*)(w2p1);
    floatx4 a3 = *(const floatx4*)(w2p1 + 4);

    #pragma unroll 2
    for (int ii = 0; ii < 16; ++ii) {
        const int i = i0 + ii;
        floatx4 n0, n1, n2, n3;
        if (ii < 15) {
            const float* np0 = w2p0 + (ii + 1) * (H_ * H_);
            const float* np1 = w2p1 + (ii + 1) * (H_ * H_);
            n0 = *(const floatx4*)(np0);
            n1 = *(const floatx4*)(np0 + 4);
            n2 = *(const floatx4*)(np1);
            n3 = *(const floatx4*)(np1 + 4);
        }
        H8 bf0, bf1;
        bf0.u[0] = pkrtz(a0[0], a0[1]);  bf0.u[1] = pkrtz(a0[2], a0[3]);
        bf0.u[2] = pkrtz(a1[0], a1[1]);  bf0.u[3] = pkrtz(a1[2], a1[3]);
        bf1.u[0] = pkrtz(a2[0], a2[1]);  bf1.u[1] = pkrtz(a2[2], a2[3]);
        bf1.u[2] = pkrtz(a3[0], a3[1]);  bf1.u[3] = pkrtz(a3[2], a3[3]);
        H8 w1v, b1v;
        w1v.v8 = *(const halfx8*)(w1s + i * H_ + koff);
        b1v.v8 = *(const halfx8*)(b1s + i * H_ + koff);
        halfx2 q0 = __builtin_bit_cast(halfx2, wbs[i * H_ + col]);
        halfx2 q1 = __builtin_bit_cast(halfx2, wbs[i * H_ + col + 16]);
        float w3e0 = (float)q0[0], b2c0 = (float)q0[1];
        float w3e1 = (float)q1[0], b2c1 = (float)q1[1];
        float p0 = 0.505f * w3e0, nn0 = 0.495f * w3e0;
        float p1 = 0.505f * w3e1, nn1 = 0.495f * w3e1;
        #pragma unroll
        for (int m = 0; m < 2; ++m) {
            halfx2 xx = __builtin_bit_cast(halfx2, xsp[(m * 16 + col) * XSTR + i]);
            H8 af;
            #pragma unroll
            for (int j = 0; j < 4; ++j) {
                halfx2 h = __builtin_elementwise_fma(xx, w1v.v2[j], b1v.v2[j]);
                af.v2[j] = __builtin_elementwise_max(h, h * slope);
            }
            floatx4 c0 = { b2c0, b2c0, b2c0, b2c0 };
            floatx4 c1 = { b2c1, b2c1, b2c1, b2c1 };
            c0 = __builtin_amdgcn_mfma_f32_16x16x32_f16(af.v8, bf0.v8, c0, 0, 0, 0);
            c1 = __builtin_amdgcn_mfma_f32_16x16x32_f16(af.v8, bf1.v8, c1, 0, 0, 0);
            #pragma unroll
            for (int r = 0; r < 4; ++r) {
                float acc = pacc[m][r];
                acc = fmaf(p0,  c0[r],
                      fmaf(nn0, fabsf(c0[r]),
                      fmaf(p1,  c1[r],
                      fmaf(nn1, fabsf(c1[r]), acc))));
                pacc[m][r] = acc;
            }
        }
        a0 = n0; a1 = n1; a2 = n2; a3 = n3;
    }
    #pragma unroll
    for (int m = 0; m < 2; ++m) {
        #pragma unroll
        for (int r = 0; r < 4; ++r) {
            float v = pacc[m][r];
            v += __shfl_xor(v, 1, 64);
            v += __shfl_xor(v, 2, 64);
            v += __shfl_xor(v, 4, 64);
            v += __shfl_xor(v, 8, 64);
            if (col == 0)
                part[wave][m * 16 + kh * 4 + r] = v;
        }
    }
    {
        const int row = t & 31, seg = t >> 5;
        float s = 0.f;
        const float* bwp = bw + o * NI;
        const float* lp  = lw + o * NI;
        const float* b3p = b3 + o * NI;
        #pragma unroll
        for (int u = 0; u < 8; ++u) {
            int i = seg * 8 + u;
            halfx2 hx = __builtin_bit_cast(halfx2, xsp[row * XSTR + i]);
            s += bwp[i] * leaky((float)hx[0]) + lp[i] * b3p[i];
        }
        rcs[seg][row] = s;
    }
    __syncthreads();
    if (t < 32) {
        float v = 0.f;
        #pragma unroll
        for (int w = 0; w < 4; ++w) v += part[w][t];
        #pragma unroll
        for (int s = 0; s < 8; ++s) v += rcs[s][t];
        out[(size_t)(row0 + t) * NO + o] = v;
    }
}

extern "C" void kernel_launch(void* const* d_in, const int* in_sizes, int n_in,
                              void* d_out, int out_size, void* d_ws, size_t ws_size,
                              hipStream_t stream) {
    const float* x  = (const float*)d_in[0];
    const float* W1 = (const float*)d_in[1];
    const float* b1 = (const float*)d_in[2];
    const float* W2 = (const float*)d_in[3];
    const float* b2 = (const float*)d_in[4];
    const float* W3 = (const float*)d_in[5];
    const float* b3 = (const float*)d_in[6];
    const float* lw = (const float*)d_in[7];
    const float* bw = (const float*)d_in[8];
    float* out = (float*)d_out;

    if (d_ws && ws_size >= (size_t)WS_NEED) {
        char* w = (char*)d_ws;
        _Float16*     w2h = (_Float16*)(w + W2H_OFF);
        _Float16*     qsg = (_Float16*)(w + QS_OFF);
        float*        rb  = (float*)(w + RB_OFF);
        unsigned int* xd  = (unsigned int*)(w + XD_OFF);
        _Float16*     w1h = (_Float16*)(w + W1H_OFF);
        _Float16*     b1h = (_Float16*)(w + B1H_OFF);
        unsigned int* wbp = (unsigned int*)(w + WBP_OFF);
        kan_pre<<<dim3(2832), dim3(256), 0, stream>>>(x, W1, b1, W2, b2, W3, lw,
                                                      w2h, qsg, rb, xd, w1h, b1h, wbp);
        dim3 grid(NO, NB / ROWS);   // 2048 blocks, o fastest (XCD-local), 5/CU
        kan_kernel<<<grid, dim3(256), 0, stream>>>(xd, w1h, b1h, wbp, qsg, rb,
                                                   b3, lw, bw, w2h, out);
    } else {
        dim3 grid(NO, NB / 32);     // fallback: R16 config
        kan_fb<<<grid, dim3(256), 0, stream>>>(x, W1, b1, W2, b2, W3, b3, lw, bw, out);
    }
}

// Round 9
// 111.646 us; speedup vs baseline: 1.0123x; 1.0123x over previous
//
#include <hip/hip_runtime.h>

// KANLayer: B=1024, I=64, O=64, H=32. ALL I/O float32 (per reference).
// out[b,o] = sum_i [ bw[o,i]*leaky(x[b,i]) + lw[o,i]*( sum_k W3[o,i,k]*h2[k] + b3[o,i] ) ]
//   h1[h] = leaky(x[b,i]*W1[o,i,h] + b1[o,i,h])
//   h2[k] = leaky(sum_h h1[h]*W2[o,i,k,h] + b2[o,i,k])
//
// R21 = R19 config (ROWS=64/MT=4 — R20's ROWS=32 TLP test came back
// neutral-worse, wave-count exhausted) + one-deep LDS-operand prefetch.
// Main is 25% issue-busy / 75% stall; the exposed latency is the per-ii
// LDS head chain (7 ds_reads -> pk-fma -> MFMA -> fma). Global W2 is
// already prefetched one-deep (R13 idiom, never spilled); R21 extends the
// SAME prime + if(ii<15) + swap idiom to w1v/b1v/qf/wbs/xsp. +~18 VGPR
// (est 75->93) under the 128 cap. NOT a pipeline rewrite (R17's spill was
// full 16-body unroll, not prefetch depth).
// Verify order: (1) kan_kernel NOT in top-5 & VGPR 85-100 (no spill;
// if ~400us -> revert R19), (2) main 29->24-26, total 105-108,
// (3) neutral -> LDS latency exonerated, loop near structural floor.

#define H_   32
#define NI   64
#define NO   64
#define NB   1024
#define ROWS 64     // batch rows per block (4 m-tiles)
#define MT   4      // m-tiles per wave
#define XSTR 66     // x LDS row stride (uint pairs): 8B-aligned, 2-way banks (free)
#define NWAVE 4
#define ISL  16     // i-slice width per wave

// ---- workspace layout (bytes) ----
#define W2H_OFF 0
#define W2H_BYTES 8388608            // 64*64*1024 f16 frags = 8.4 MB
#define QS_OFF   8388608
#define QS_BYTES 262144              // 64*64*32 f16
#define RB_OFF   8650752
#define RB_BYTES 16384               // 64*64 f32
#define XD_OFF   8667136
#define XD_BYTES 262144              // 1024*64 dup-f16 pairs (u32)
#define W1H_OFF  8929280
#define W1H_BYTES 262144             // 64*64*32 f16
#define B1H_OFF  9191424
#define B1H_BYTES 262144
#define WBP_OFF  9453568
#define WBP_BYTES 524288             // 64*64*32 u32 pairs
#define WS_NEED  9977856

typedef float    floatx4 __attribute__((ext_vector_type(4)));
typedef _Float16 halfx8  __attribute__((ext_vector_type(8)));
typedef _Float16 halfx2  __attribute__((ext_vector_type(2)));

union H8 { halfx8 v8; halfx2 v2[4]; unsigned int u[4]; };

__device__ inline float leaky(float v) { return fmaxf(v, 0.01f * v); }

__device__ inline unsigned int pkrtz(float a, float b) {   // (a,b) -> f16x2, RTZ
    return __builtin_bit_cast(unsigned int, __builtin_amdgcn_cvt_pkrtz(a, b));
}

// ================= pre-kernel (R19 verbatim) =================
// ranges: [0,524288) W2 repack; +131072 q; +4096 rb; +16384 xd; +16384 w1h;
//         +16384 b1h; +16384 wbp.  total 724992 thr = 2832 blocks.
__global__ __launch_bounds__(256)
void kan_pre(const float* __restrict__ x,  const float* __restrict__ W1,
             const float* __restrict__ b1, const float* __restrict__ W2,
             const float* __restrict__ b2, const float* __restrict__ W3,
             const float* __restrict__ lw,
             _Float16* __restrict__ w2h, _Float16* __restrict__ qs,
             float* __restrict__ rb, unsigned int* __restrict__ xd,
             _Float16* __restrict__ w1h, _Float16* __restrict__ b1h,
             unsigned int* __restrict__ wbp)
{
    const int tid = blockIdx.x * 256 + threadIdx.x;
    if (tid < 524288) {
        // W2 -> f16 MFMA fragments, dest-linear: tid -> (o,i,f,lane)
        const int lane = tid & 63, f = (tid >> 6) & 1, i = (tid >> 7) & 63, o = tid >> 13;
        const int col = lane & 15, kh = lane >> 4;
        const float* src = W2 + (((size_t)(o * 64 + i) * 32 + f * 16 + col) * 32 + kh * 8);
        float4 s0 = *(const float4*)src;
        float4 s1 = *(const float4*)(src + 4);
        uint4 p = { pkrtz(s0.x, s0.y), pkrtz(s0.z, s0.w),
                    pkrtz(s1.x, s1.y), pkrtz(s1.z, s1.w) };
        *(uint4*)(w2h + (size_t)tid * 8) = p;
    } else if (tid < 655360) {
        // q[oi,h] = .505*lw*sum_k w3_k*W2[k,h]
        const int qt = tid - 524288;
        const int h = qt & 31, oi = qt >> 5;
        const float* w2p = W2 + (size_t)oi * 1024 + h;
        const float* w3p = W3 + (size_t)oi * 32;
        float acc = 0.f;
        #pragma unroll 8
        for (int k = 0; k < 32; ++k) acc += w3p[k] * w2p[k * 32];
        qs[(size_t)oi * 32 + h] = (_Float16)(0.505f * lw[oi] * acc);
    } else if (tid < 659456) {
        // rbias[oi] = .505*lw*sum_k w3_k*b2_k
        const int oi = tid - 655360;
        const float* w3p = W3 + (size_t)oi * 32;
        const float* b2p = b2 + (size_t)oi * 32;
        float acc = 0.f;
        #pragma unroll 8
        for (int k = 0; k < 32; ++k) acc += w3p[k] * b2p[k];
        rb[oi] = 0.505f * lw[oi] * acc;
    } else if (tid < 675840) {
        // x -> duplicated f16 pairs
        const int j = tid - 659456;
        const int fe = j * 4;
        float4 xv = *(const float4*)(x + fe);
        uint4 p = { pkrtz(xv.x, xv.x), pkrtz(xv.y, xv.y),
                    pkrtz(xv.z, xv.z), pkrtz(xv.w, xv.w) };
        *(uint4*)(xd + fe) = p;
    } else if (tid < 692224) {
        // W1 -> f16
        const int j = tid - 675840;
        const float* s = W1 + (size_t)j * 8;
        float4 a = *(const float4*)s, c = *(const float4*)(s + 4);
        uint4 p = { pkrtz(a.x, a.y), pkrtz(a.z, a.w),
                    pkrtz(c.x, c.y), pkrtz(c.z, c.w) };
        *(uint4*)(w1h + (size_t)j * 8) = p;
    } else if (tid < 708608) {
        // b1 -> f16
        const int j = tid - 692224;
        const float* s = b1 + (size_t)j * 8;
        float4 a = *(const float4*)s, c = *(const float4*)(s + 4);
        uint4 p = { pkrtz(a.x, a.y), pkrtz(a.z, a.w),
                    pkrtz(c.x, c.y), pkrtz(c.z, c.w) };
        *(uint4*)(b1h + (size_t)j * 8) = p;
    } else if (tid < 724992) {
        // wbp[oi*32+k] = pk(.495*lw*w3, b2)
        const int j = tid - 708608;
        const int e = j * 8, oi = e >> 5;
        const float l = 0.495f * lw[oi];
        const float* w3g = W3 + e;
        const float* b2g = b2 + e;
        float4 wa = *(const float4*)(w3g), wb = *(const float4*)(w3g + 4);
        float4 ba = *(const float4*)(b2g), bb = *(const float4*)(b2g + 4);
        uint4 p0 = { pkrtz(l * wa.x, ba.x), pkrtz(l * wa.y, ba.y),
                     pkrtz(l * wa.z, ba.z), pkrtz(l * wa.w, ba.w) };
        uint4 p1 = { pkrtz(l * wb.x, bb.x), pkrtz(l * wb.y, bb.y),
                     pkrtz(l * wb.z, bb.z), pkrtz(l * wb.w, bb.w) };
        *(uint4*)(&wbp[e])     = p0;
        *(uint4*)(&wbp[e + 4]) = p1;
    }
}

// ================= main kernel (R19 + one-deep LDS prefetch) =================
__global__ __launch_bounds__(256, 4)
void kan_kernel(const unsigned int* __restrict__ xd, const _Float16* __restrict__ w1h,
                const _Float16* __restrict__ b1h, const unsigned int* __restrict__ wbp,
                const _Float16* __restrict__ qsg, const float* __restrict__ rb,
                const float* __restrict__ b3,  const float* __restrict__ lw,
                const float* __restrict__ bw,  const _Float16* __restrict__ w2h,
                float* __restrict__ out)
{
    __shared__ unsigned int xsp[ROWS * XSTR];  // x dup-f16 pairs, 16.9 KB
    __shared__ _Float16 w1s[NI * H_];          // 4 KB
    __shared__ _Float16 b1s[NI * H_];          // 4 KB
    __shared__ unsigned int wbs[NI * H_];      // {.495*lw*w3, b2} f16 pairs, 8 KB
    __shared__ _Float16 qsl[NI * H_];          // q staged, 4 KB
    __shared__ float rcs[NWAVE][ROWS];         // per-seg row constants, 1 KB
    __shared__ float part[NWAVE][ROWS];        // per-wave i-slice partials, 1 KB

    const int t    = threadIdx.x;
    const int o    = blockIdx.x;               // o fastest -> same-o blocks share XCD
    const int row0 = blockIdx.y * ROWS;

    // ---- stage x tile: pure copy from pre-converted xd ----
    const unsigned int* xdp = xd + (size_t)row0 * NI;
    #pragma unroll
    for (int v = 0; v < 4; ++v) {
        int fe = (v * 256 + t) * 4;            // u32 index, multiple of 4
        int r = fe >> 6, c = fe & 63;
        uint4 w = *(const uint4*)(xdp + fe);
        uint2 lo = { w.x, w.y };
        uint2 hi = { w.z, w.w };
        *(uint2*)(&xsp[r * XSTR + c])     = lo;   // 66r+c even -> 8B aligned
        *(uint2*)(&xsp[r * XSTR + c + 2]) = hi;
    }
    // ---- stage W1/b1/wbs/q: pure copies ----
    *(uint4*)(w1s + t * 8) = *(const uint4*)(w1h + (size_t)o * (NI * H_) + t * 8);
    *(uint4*)(b1s + t * 8) = *(const uint4*)(b1h + (size_t)o * (NI * H_) + t * 8);
    {
        const unsigned int* wp = wbp + (size_t)o * (NI * H_);  // o*2048
        *(uint4*)(&wbs[t * 8])     = *(const uint4*)(wp + t * 8);
        *(uint4*)(&wbs[t * 8 + 4]) = *(const uint4*)(wp + t * 8 + 4);
    }
    *(uint4*)(qsl + t * 8) = *(const uint4*)(qsg + (size_t)o * (NI * H_) + t * 8);
    __syncthreads();

    const int lane = t & 63, wave = t >> 6;
    const int col  = lane & 15;            // MFMA n-index (h2 k-slot) / A m-offset
    const int kh   = lane >> 4;            // contraction quad
    const int koff = kh * 8;
    const int i0   = wave * ISL;           // this wave's i-slice (16 wide)

    const halfx2 slope = { (_Float16)0.01f, (_Float16)0.01f };

    floatx4 pacc[MT];                      // |c| (negative-half) accumulators
    floatx4 acc1[MT];                      // q-MFMA (positive-half) accumulators
    #pragma unroll
    for (int m = 0; m < MT; ++m) {
        pacc[m] = floatx4{0.f, 0.f, 0.f, 0.f};
        acc1[m] = floatx4{0.f, 0.f, 0.f, 0.f};
    }

    // W2 f16 fragments: elem = (o*NI+i)*1024 + f*512 + lane*8
    const _Float16* wbase = w2h + (size_t)(o * NI + i0) * 1024 + (size_t)lane * 8;

    // ---- prime ALL prefetch registers with iter 0's operands ----
    halfx8 cA = *(const halfx8*)(wbase);                     // global W2
    halfx8 cB = *(const halfx8*)(wbase + 512);
    H8 w1c, b1c, qfc;                                        // LDS operands
    w1c.v8 = *(const halfx8*)(w1s + i0 * H_ + koff);
    b1c.v8 = *(const halfx8*)(b1s + i0 * H_ + koff);
    qfc.v8 = *(const halfx8*)(qsl + i0 * H_ + koff);
    unsigned int wb0c = wbs[i0 * H_ + col];
    unsigned int wb1c = wbs[i0 * H_ + col + 16];
    unsigned int xxc[MT];
    #pragma unroll
    for (int m = 0; m < MT; ++m)
        xxc[m] = xsp[(m * 16 + col) * XSTR + i0];

    #pragma unroll 2
    for (int ii = 0; ii < ISL; ++ii) {
        // ---- issue next iteration's loads (global + LDS) before consuming ----
        halfx8 nA, nB;
        H8 w1n, b1n, qfn;
        unsigned int wb0n, wb1n, xxn[MT];
        if (ii < ISL - 1) {
            const int in = i0 + ii + 1;
            const _Float16* np = wbase + (ii + 1) * 1024;
            nA = *(const halfx8*)(np);
            nB = *(const halfx8*)(np + 512);
            w1n.v8 = *(const halfx8*)(w1s + in * H_ + koff);
            b1n.v8 = *(const halfx8*)(b1s + in * H_ + koff);
            qfn.v8 = *(const halfx8*)(qsl + in * H_ + koff);
            wb0n = wbs[in * H_ + col];
            wb1n = wbs[in * H_ + col + 16];
            #pragma unroll
            for (int m = 0; m < MT; ++m)
                xxn[m] = xsp[(m * 16 + col) * XSTR + in];
        }

        // ---- consume current iteration's prefetched operands ----
        halfx2 q0 = __builtin_bit_cast(halfx2, wb0c);
        halfx2 q1 = __builtin_bit_cast(halfx2, wb1c);
        float nn0 = (float)q0[0], b2c0 = (float)q0[1];
        float nn1 = (float)q1[0], b2c1 = (float)q1[1];

        #pragma unroll
        for (int m = 0; m < MT; ++m) {
            halfx2 xx = __builtin_bit_cast(halfx2, xxc[m]);
            H8 af;
            #pragma unroll
            for (int j = 0; j < 4; ++j) {
                halfx2 h = __builtin_elementwise_fma(xx, w1c.v2[j], b1c.v2[j]);
                af.v2[j] = __builtin_elementwise_max(h, h * slope);  // pk leaky
            }
            floatx4 c0 = { b2c0, b2c0, b2c0, b2c0 };   // b2 folded into C
            floatx4 c1 = { b2c1, b2c1, b2c1, b2c1 };
            c0 = __builtin_amdgcn_mfma_f32_16x16x32_f16(af.v8, cA, c0, 0, 0, 0);
            c1 = __builtin_amdgcn_mfma_f32_16x16x32_f16(af.v8, cB, c1, 0, 0, 0);
            acc1[m] = __builtin_amdgcn_mfma_f32_16x16x32_f16(af.v8, qfc.v8, acc1[m], 0, 0, 0);
            // negative-half epilogue only: pacc += (.495*lw*w3)*|c|
            #pragma unroll
            for (int r = 0; r < 4; ++r)
                pacc[m][r] = fmaf(nn0, fabsf(c0[r]),
                             fmaf(nn1, fabsf(c1[r]), pacc[m][r]));
        }

        cA = nA; cB = nB;
        w1c = w1n; b1c = b1n; qfc = qfn;
        wb0c = wb0n; wb1c = wb1n;
        #pragma unroll
        for (int m = 0; m < MT; ++m) xxc[m] = xxn[m];
    }

    // ---- in-wave reduce over the 16 col lanes, deposit i-slice partials ----
    // acc1 columns are identical (broadcast B) -> add once at col==0, no reduce.
    #pragma unroll
    for (int m = 0; m < MT; ++m) {
        #pragma unroll
        for (int r = 0; r < 4; ++r) {
            float v = pacc[m][r];
            v += __shfl_xor(v, 1, 64);
            v += __shfl_xor(v, 2, 64);
            v += __shfl_xor(v, 4, 64);
            v += __shfl_xor(v, 8, 64);
            if (col == 0)
                part[wave][m * 16 + kh * 4 + r] = v + acc1[m][r];  // C row = kh*4+r
        }
    }

    // ---- per-row constants, 4-way parallel over i-segments ----
    {
        const int row = t & 63, seg = t >> 6;
        float s = 0.f;
        const float* bwp = bw + o * NI;
        const float* lp  = lw + o * NI;
        const float* b3p = b3 + o * NI;
        const float* rbp = rb + o * NI;
        #pragma unroll
        for (int u = 0; u < NI / NWAVE; ++u) {
            int i = seg * (NI / NWAVE) + u;
            halfx2 hx = __builtin_bit_cast(halfx2, xsp[row * XSTR + i]);
            s += bwp[i] * leaky((float)hx[0]) + lp[i] * b3p[i] + rbp[i];
        }
        rcs[seg][row] = s;
    }
    __syncthreads();

    // ---- cross-wave sum + per-row constants, write out[b,o] ----
    if (t < ROWS) {
        float v = 0.f;
        #pragma unroll
        for (int w = 0; w < NWAVE; ++w) v += part[w][t] + rcs[w][t];
        out[(size_t)(row0 + t) * NO + o] = v;
    }
}

// ================= fallback (R16 verbatim, no workspace) =================
__global__ __launch_bounds__(256, 6)
void kan_fb(const float* __restrict__ x,  const float* __restrict__ W1,
            const float* __restrict__ b1, const float* __restrict__ W2,
            const float* __restrict__ b2, const float* __restrict__ W3,
            const float* __restrict__ b3, const float* __restrict__ lw,
            const float* __restrict__ bw, float* __restrict__ out)
{
    __shared__ unsigned int xsp[32 * XSTR];
    __shared__ _Float16 w1s[NI * H_];
    __shared__ _Float16 b1s[NI * H_];
    __shared__ unsigned int wbs[NI * H_];
    __shared__ float rcs[8][32];
    __shared__ float part[4][32];

    const int t    = threadIdx.x;
    const int o    = blockIdx.x;
    const int row0 = blockIdx.y * 32;

    const float* xsrc = x + (size_t)row0 * NI;
    #pragma unroll
    for (int v = 0; v < 2; ++v) {
        int fe = (v * 256 + t) * 4;
        int r = fe >> 6, c = fe & 63;
        float4 xv = *(const float4*)(xsrc + fe);
        uint2 lo = { pkrtz(xv.x, xv.x), pkrtz(xv.y, xv.y) };
        uint2 hi = { pkrtz(xv.z, xv.z), pkrtz(xv.w, xv.w) };
        *(uint2*)(&xsp[r * XSTR + c])     = lo;
        *(uint2*)(&xsp[r * XSTR + c + 2]) = hi;
    }
    const float* w1g = W1 + (size_t)o * NI * H_;
    const float* b1g = b1 + (size_t)o * NI * H_;
    #pragma unroll
    for (int v = 0; v < 2; ++v) {
        int e = (v * 256 + t) * 4;
        float4 a = *(const float4*)(w1g + e);
        float4 c = *(const float4*)(b1g + e);
        uint2 pa = { pkrtz(a.x, a.y), pkrtz(a.z, a.w) };
        uint2 pc = { pkrtz(c.x, c.y), pkrtz(c.z, c.w) };
        *(uint2*)(w1s + e) = pa;
        *(uint2*)(b1s + e) = pc;
    }
    {
        int e = t * 8;
        float l = lw[o * NI + (e >> 5)];
        const float* w3g = W3 + (size_t)o * NI * H_ + e;
        const float* b2g = b2 + (size_t)o * NI * H_ + e;
        float4 wa = *(const float4*)(w3g), wb = *(const float4*)(w3g + 4);
        float4 ba = *(const float4*)(b2g), bb = *(const float4*)(b2g + 4);
        uint4 p0 = { pkrtz(l * wa.x, ba.x), pkrtz(l * wa.y, ba.y),
                     pkrtz(l * wa.z, ba.z), pkrtz(l * wa.w, ba.w) };
        uint4 p1 = { pkrtz(l * wb.x, bb.x), pkrtz(l * wb.y, bb.y),
                     pkrtz(l * wb.z, bb.z), pkrtz(l * wb.w, bb.w) };
        *(uint4*)(&wbs[e])     = p0;
        *(uint4*)(&wbs[e + 4]) = p1;
    }
    __syncthreads();

    const int lane = t & 63, wave = t >> 6;
    const int col  = lane & 15;
    const int kh   = lane >> 4;
    const int koff = kh * 8;
    const int i0   = wave * 16;

    const float* w2p0 = W2 + ((size_t)(o * NI + i0) * H_ + col) * H_ + koff;
    const float* w2p1 = w2p0 + 16 * H_;
    const halfx2 slope = { (_Float16)0.01f, (_Float16)0.01f };

    floatx4 pacc[2];
    #pragma unroll
    for (int m = 0; m < 2; ++m) pacc[m] = floatx4{0.f, 0.f, 0.f, 0.f};

    floatx4 a0 = *(const floatx4*)(w2p0);
    floatx4 a1 = *(const floatx4*)(w2p0 + 4);
    floatx4 a2 = *(const floatx4*)(w2p1);
    floatx4 a3 = *(const floatx4*)(w2p1 + 4);

    #pragma unroll 2
    for (int ii = 0; ii < 16; ++ii) {
        const int i = i0 + ii;
        floatx4 n0, n1, n2, n3;
        if (ii < 15) {
            const float* np0 = w2p0 + (ii + 1) * (H_ * H_);
            const float* np1 = w2p1 + (ii + 1) * (H_ * H_);
            n0 = *(const floatx4*)(np0);
            n1 = *(const floatx4*)(np0 + 4);
            n2 = *(const floatx4*)(np1);
            n3 = *(const floatx4*)(np1 + 4);
        }
        H8 bf0, bf1;
        bf0.u[0] = pkrtz(a0[0], a0[1]);  bf0.u[1] = pkrtz(a0[2], a0[3]);
        bf0.u[2] = pkrtz(a1[0], a1[1]);  bf0.u[3] = pkrtz(a1[2], a1[3]);
        bf1.u[0] = pkrtz(a2[0], a2[1]);  bf1.u[1] = pkrtz(a2[2], a2[3]);
        bf1.u[2] = pkrtz(a3[0], a3[1]);  bf1.u[3] = pkrtz(a3[2], a3[3]);
        H8 w1v, b1v;
        w1v.v8 = *(const halfx8*)(w1s + i * H_ + koff);
        b1v.v8 = *(const halfx8*)(b1s + i * H_ + koff);
        halfx2 q0 = __builtin_bit_cast(halfx2, wbs[i * H_ + col]);
        halfx2 q1 = __builtin_bit_cast(halfx2, wbs[i * H_ + col + 16]);
        float w3e0 = (float)q0[0], b2c0 = (float)q0[1];
        float w3e1 = (float)q1[0], b2c1 = (float)q1[1];
        float p0 = 0.505f * w3e0, nn0 = 0.495f * w3e0;
        float p1 = 0.505f * w3e1, nn1 = 0.495f * w3e1;
        #pragma unroll
        for (int m = 0; m < 2; ++m) {
            halfx2 xx = __builtin_bit_cast(halfx2, xsp[(m * 16 + col) * XSTR + i]);
            H8 af;
            #pragma unroll
            for (int j = 0; j < 4; ++j) {
                halfx2 h = __builtin_elementwise_fma(xx, w1v.v2[j], b1v.v2[j]);
                af.v2[j] = __builtin_elementwise_max(h, h * slope);
            }
            floatx4 c0 = { b2c0, b2c0, b2c0, b2c0 };
            floatx4 c1 = { b2c1, b2c1, b2c1, b2c1 };
            c0 = __builtin_amdgcn_mfma_f32_16x16x32_f16(af.v8, bf0.v8, c0, 0, 0, 0);
            c1 = __builtin_amdgcn_mfma_f32_16x16x32_f16(af.v8, bf1.v8, c1, 0, 0, 0);
            #pragma unroll
            for (int r = 0; r < 4; ++r) {
                float acc = pacc[m][r];
                acc = fmaf(p0,  c0[r],
                      fmaf(nn0, fabsf(c0[r]),
                      fmaf(p1,  c1[r],
                      fmaf(nn1, fabsf(c1[r]), acc))));
                pacc[m][r] = acc;
            }
        }
        a0 = n0; a1 = n1; a2 = n2; a3 = n3;
    }
    #pragma unroll
    for (int m = 0; m < 2; ++m) {
        #pragma unroll
        for (int r = 0; r < 4; ++r) {
            float v = pacc[m][r];
            v += __shfl_xor(v, 1, 64);
            v += __shfl_xor(v, 2, 64);
            v += __shfl_xor(v, 4, 64);
            v += __shfl_xor(v, 8, 64);
            if (col == 0)
                part[wave][m * 16 + kh * 4 + r] = v;
        }
    }
    {
        const int row = t & 31, seg = t >> 5;
        float s = 0.f;
        const float* bwp = bw + o * NI;
        const float* lp  = lw + o * NI;
        const float* b3p = b3 + o * NI;
        #pragma unroll
        for (int u = 0; u < 8; ++u) {
            int i = seg * 8 + u;
            halfx2 hx = __builtin_bit_cast(halfx2, xsp[row * XSTR + i]);
            s += bwp[i] * leaky((float)hx[0]) + lp[i] * b3p[i];
        }
        rcs[seg][row] = s;
    }
    __syncthreads();
    if (t < 32) {
        float v = 0.f;
        #pragma unroll
        for (int w = 0; w < 4; ++w) v += part[w][t];
        #pragma unroll
        for (int s = 0; s < 8; ++s) v += rcs[s][t];
        out[(size_t)(row0 + t) * NO + o] = v;
    }
}

extern "C" void kernel_launch(void* const* d_in, const int* in_sizes, int n_in,
                              void* d_out, int out_size, void* d_ws, size_t ws_size,
                              hipStream_t stream) {
    const float* x  = (const float*)d_in[0];
    const float* W1 = (const float*)d_in[1];
    const float* b1 = (const float*)d_in[2];
    const float* W2 = (const float*)d_in[3];
    const float* b2 = (const float*)d_in[4];
    const float* W3 = (const float*)d_in[5];
    const float* b3 = (const float*)d_in[6];
    const float* lw = (const float*)d_in[7];
    const float* bw = (const float*)d_in[8];
    float* out = (float*)d_out;

    if (d_ws && ws_size >= (size_t)WS_NEED) {
        char* w = (char*)d_ws;
        _Float16*     w2h = (_Float16*)(w + W2H_OFF);
        _Float16*     qsg = (_Float16*)(w + QS_OFF);
        float*        rb  = (float*)(w + RB_OFF);
        unsigned int* xd  = (unsigned int*)(w + XD_OFF);
        _Float16*     w1h = (_Float16*)(w + W1H_OFF);
        _Float16*     b1h = (_Float16*)(w + B1H_OFF);
        unsigned int* wbp = (unsigned int*)(w + WBP_OFF);
        kan_pre<<<dim3(2832), dim3(256), 0, stream>>>(x, W1, b1, W2, b2, W3, lw,
                                                      w2h, qsg, rb, xd, w1h, b1h, wbp);
        dim3 grid(NO, NB / ROWS);   // 1024 blocks, o fastest (XCD-local), 4/CU
        kan_kernel<<<grid, dim3(256), 0, stream>>>(xd, w1h, b1h, wbp, qsg, rb,
                                                   b3, lw, bw, w2h, out);
    } else {
        dim3 grid(NO, NB / 32);     // fallback: R16 config
        kan_fb<<<grid, dim3(256), 0, stream>>>(x, W1, b1, W2, b2, W3, b3, lw, bw, out);
    }
}